// Round 1
// 140.429 us; speedup vs baseline: 1.0374x; 1.0374x over previous
//
#include <hip/hip_runtime.h>
#include <hip/hip_bf16.h>
#include <math.h>

#define BB 8
#define TT 2048
#define CC 1024
#define HH 64
#define BT (BB * TT)   // 16384 rows

typedef __attribute__((ext_vector_type(8))) short short8;   // bf16 x8 MFMA frag
typedef __attribute__((ext_vector_type(4))) float floatx4;  // MFMA acc

static __device__ inline ushort f2bf(float f) {
    __hip_bfloat16 h = __float2bfloat16(f);
    return *reinterpret_cast<ushort*>(&h);
}
static __device__ inline unsigned int f2bf2(float lo, float hi) {
    __hip_bfloat162 h = __float22bfloat162_rn(make_float2(lo, hi));
    return *reinterpret_cast<unsigned int*>(&h);
}
static __device__ inline float bf2f(ushort u) {
    union { unsigned int i; float f; } c;
    c.i = ((unsigned int)u) << 16;
    return c.f;
}
// async global->LDS DMA, 16 B per lane.  LDS dest = wave-uniform base + lane*16.
static __device__ inline void gl_lds16(const ushort* g, ushort* l) {
    __builtin_amdgcn_global_load_lds(
        (const __attribute__((address_space(1))) unsigned int*)g,
        (__attribute__((address_space(3))) unsigned int*)l,
        16, 0, 0);
}

// ---------------------------------------------------------------------------
// Kernel 0: W prep (coalesced).  W[k][n] fp32 -> WbT[m][n][k] bf16.
// 48 blocks (was 24): 64-row k-chunks so more CUs participate.
// ---------------------------------------------------------------------------
__global__ __launch_bounds__(256) void wprep_kernel(
    const float* __restrict__ Wq, const float* __restrict__ Wk,
    const float* __restrict__ Wv, ushort* __restrict__ WbT)
{
    __shared__ float ws_[64 * 65];
    const int m  = blockIdx.x >> 4;          // 0..2
    const int kb = (blockIdx.x & 15) * 64;   // 0..960
    const float* W = (m == 0) ? Wq : (m == 1) ? Wk : Wv;
    const int t  = threadIdx.x;
    const int lr = t >> 4, lc = (t & 15) * 4;
    #pragma unroll
    for (int i = 0; i < 4; ++i) {
        const int row = lr + i * 16;
        float4 v = *(const float4*)&W[(size_t)(kb + row) * HH + lc];
        ws_[row * 65 + lc + 0] = v.x; ws_[row * 65 + lc + 1] = v.y;
        ws_[row * 65 + lc + 2] = v.z; ws_[row * 65 + lc + 3] = v.w;
    }
    __syncthreads();
    const int n = t & 63, kseg = t >> 6;     // kseg 0..3 -> 16 k each
    union { ushort s[16]; uint4 q[2]; } u;
    #pragma unroll
    for (int j = 0; j < 16; ++j)
        u.s[j] = f2bf(ws_[(kseg * 16 + j) * 65 + n]);
    ushort* dst = &WbT[(size_t)(m * 64 + n) * 1024 + kb + kseg * 16];
    *(uint4*)&dst[0] = u.q[0];
    *(uint4*)&dst[8] = u.q[1];
}

// ---------------------------------------------------------------------------
// Kernel 1: QKV via bf16 MFMA.  Change this round: x register prefetch is
// 2 iterations deep (was 1).  qkv has no global_load_lds, so __syncthreads
// only drains lgkmcnt -> the x loads stay in flight across the barrier and
// get ~2 full iterations (~800 cy) of cover vs ~900 cy HBM latency.
// ---------------------------------------------------------------------------
__global__ __launch_bounds__(256) void qkv_kernel(
    const float* __restrict__ x, const ushort* __restrict__ WbT,
    ushort* __restrict__ qb, ushort* __restrict__ kbS, ushort* __restrict__ vS)
{
    __shared__ ushort As[2][256 * 8];   // frag-major: slot = (p*2+mt)*64 + l16*4 + quad

    const int row0 = blockIdx.x * 32;
    const int t    = threadIdx.x;
    const int w    = t >> 6;
    const int lane = t & 63;
    const int l16  = lane & 15;
    const int quad = lane >> 4;
    const int ct0  = w * 3;

    const int srow = t >> 3, sseg = t & 7;
    const int slot = (((sseg >> 2) * 2 + (srow >> 4)) * 16 + (srow & 15)) * 4 + (sseg & 3);
    const float* xsrc = &x[(size_t)(row0 + srow) * CC + sseg * 8];

    floatx4 acc[2][3];
    #pragma unroll
    for (int mt = 0; mt < 2; ++mt)
        #pragma unroll
        for (int c = 0; c < 3; ++c) acc[mt][c] = (floatx4){0.f, 0.f, 0.f, 0.f};

    // ---- depth-2 register prefetch of x ----
    float4 xa0 = *(const float4*)&xsrc[0];
    float4 xb0 = *(const float4*)&xsrc[4];
    float4 xa1 = *(const float4*)&xsrc[64];
    float4 xb1 = *(const float4*)&xsrc[68];

    short8 bfr[2][3];
    #pragma unroll
    for (int p = 0; p < 2; ++p)
        #pragma unroll
        for (int c = 0; c < 3; ++c)
            bfr[p][c] = *(const short8*)&WbT[(size_t)((ct0 + c) * 16 + l16) * 1024
                                             + p * 32 + quad * 8];

    auto body = [&](int it, float4& xa, float4& xb) {
        uint4 uq;
        uq.x = f2bf2(xa.x, xa.y); uq.y = f2bf2(xa.z, xa.w);
        uq.z = f2bf2(xb.x, xb.y); uq.w = f2bf2(xb.z, xb.w);
        *(uint4*)&As[it & 1][slot * 8] = uq;
        __syncthreads();

        // issue HBM loads for it+2 first (longest latency)
        if (it + 2 < 16) {
            xa = *(const float4*)&xsrc[(it + 2) * 64 + 0];
            xb = *(const float4*)&xsrc[(it + 2) * 64 + 4];
        }
        short8 bnx[2][3];
        if (it < 15) {
            const int kn = (it + 1) * 64;
            #pragma unroll
            for (int p = 0; p < 2; ++p)
                #pragma unroll
                for (int c = 0; c < 3; ++c)
                    bnx[p][c] = *(const short8*)&WbT[(size_t)((ct0 + c) * 16 + l16) * 1024
                                                     + kn + p * 32 + quad * 8];
        }

        #pragma unroll
        for (int p = 0; p < 2; ++p) {
            short8 a0 = *(const short8*)&As[it & 1][(size_t)((p * 2 + 0) * 64 + l16 * 4 + quad) * 8];
            short8 a1 = *(const short8*)&As[it & 1][(size_t)((p * 2 + 1) * 64 + l16 * 4 + quad) * 8];
            #pragma unroll
            for (int c = 0; c < 3; ++c) {
                acc[0][c] = __builtin_amdgcn_mfma_f32_16x16x32_bf16(a0, bfr[p][c], acc[0][c], 0, 0, 0);
                acc[1][c] = __builtin_amdgcn_mfma_f32_16x16x32_bf16(a1, bfr[p][c], acc[1][c], 0, 0, 0);
            }
        }
        #pragma unroll
        for (int p = 0; p < 2; ++p)
            #pragma unroll
            for (int c = 0; c < 3; ++c)
                bfr[p][c] = bnx[p][c];
    };

    for (int it2 = 0; it2 < 16; it2 += 2) {
        body(it2 + 0, xa0, xb0);
        body(it2 + 1, xa1, xb1);
    }

    // ---- epilogue ----
    const int half = (row0 >> 5) & 1;              // which 32-row half of the 64-tile
    const size_t tile = (size_t)(row0 >> 6) * 4096;
    #pragma unroll
    for (int c = 0; c < 3; ++c) {
        const int ct    = ct0 + c;
        const int mtype = ct >> 2;
        const int n0    = (ct & 3) * 16;
        #pragma unroll
        for (int mt = 0; mt < 2; ++mt) {
            const int row = row0 + mt * 16 + quad * 4;
            if (mtype == 0) {                       // q: row-major, /8 folded
                #pragma unroll
                for (int reg = 0; reg < 4; ++reg)
                    qb[(size_t)(row + reg) * HH + n0 + l16] = f2bf(acc[mt][c][reg] * 0.125f);
            } else if (mtype == 1) {                // K swizzled (B-frag order)
                const int cP    = half * 2 + mt;
                const int pP    = (ct & 3) >> 1;
                const int quadP = ((ct & 3) * 2 + (l16 >> 3)) & 3;
                const int jP    = l16 & 7;
                const int ub    = (cP * 2 + pP) * 64 + quadP * 16;
                #pragma unroll
                for (int reg = 0; reg < 4; ++reg)
                    kbS[tile + (size_t)(ub + quad * 4 + reg) * 8 + jP] = f2bf(acc[mt][c][reg]);
            } else {                                // V swizzled (B-frag order)
                const int cp2 = (ct & 3) * 2 + half;   // c'*2 + p'
                #pragma unroll
                for (int reg = 0; reg < 4; ++reg) {
                    const int rq    = quad * 4 + reg;
                    const int quadP = mt * 2 + (rq >> 3);
                    vS[tile + (size_t)(cp2 * 64 + quadP * 16 + l16) * 8 + (rq & 7)] = f2bf(acc[mt][c][reg]);
                }
            }
        }
    }
}

// ---------------------------------------------------------------------------
// Kernel 2: block-cooperative split-K MFMA flash attention (static-max).
// UNCHANGED this round (clean attribution of the delta).
// ---------------------------------------------------------------------------
__global__ __launch_bounds__(256) void attn_kernel(
    const ushort* __restrict__ qb, const ushort* __restrict__ kbS,
    const ushort* __restrict__ vS, ushort* __restrict__ Opart,
    float* __restrict__ ml)
{
    __shared__ __align__(16) ushort Kb[2][4096];     // 8 KB x2
    __shared__ __align__(16) ushort Vb[2][4096];     // 8 KB x2
    __shared__ __align__(16) ushort P[4][16 * 72];   // per-wave P tile

    const int t    = threadIdx.x;
    const int w    = t >> 6;
    const int lane = t & 63;
    const int l16  = lane & 15;
    const int quad = lane >> 4;

    const int b   = blockIdx.x & 7;
    const int idx = blockIdx.x >> 3;   // 0..79, heavy-first
    int qt, part, np;
    if (idx < 32)      { qt = 31 - (idx >> 2); part = idx & 3; np = 4; }
    else if (idx < 56) { const int u = idx - 32; const int g = u / 3;
                         qt = 23 - g; part = u - g * 3; np = 3; }
    else if (idx < 72) { const int u = idx - 56; qt = 15 - (u >> 1); part = u & 1; np = 2; }
    else               { qt = 7 - (idx - 72); part = 0; np = 1; }
    const int ntiles = qt + 1;
    const int ktb = (part * ntiles) / np;
    const int kte = ((part + 1) * ntiles) / np;

    const ushort* ktile0 = kbS + (size_t)(b * 32) * 4096;
    const ushort* vtile0 = vS  + (size_t)(b * 32) * 4096;

    // Q A-frags: rows qt*64 + w*16 + l16
    short8 qf[2];
    {
        const ushort* qrow = qb + ((size_t)b * TT + qt * 64 + w * 16) * HH;
        qf[0] = *(const short8*)&qrow[l16 * HH + quad * 8];
        qf[1] = *(const short8*)&qrow[l16 * HH + 32 + quad * 8];
    }
    short8 ones;
    #pragma unroll
    for (int i = 0; i < 8; ++i) ones[i] = (short)0x3F80;   // bf16 1.0

    floatx4 o[4], osum;
    #pragma unroll
    for (int c = 0; c < 4; ++c) o[c] = (floatx4){0.f, 0.f, 0.f, 0.f};
    osum = (floatx4){0.f, 0.f, 0.f, 0.f};

    // ---- prologue: async-stage tile ktb into buffer 0 ----
    {
        const ushort* gk = ktile0 + (size_t)ktb * 4096 + w * 1024 + lane * 8;
        const ushort* gv = vtile0 + (size_t)ktb * 4096 + w * 1024 + lane * 8;
        gl_lds16(gk,       &Kb[0][w * 1024]);
        gl_lds16(gk + 512, &Kb[0][w * 1024 + 512]);
        gl_lds16(gv,       &Vb[0][w * 1024]);
        gl_lds16(gv + 512, &Vb[0][w * 1024 + 512]);
    }

    ushort* Pw = &P[w][0];

    for (int kt = ktb; kt < kte; ++kt) {
        const int cur = (kt - ktb) & 1;
        __syncthreads();   // drains async loads of buf cur; all waves done with buf cur^1

        // ---- async prefetch of tile kt+1 into the other buffer ----
        if (kt + 1 < kte) {
            const int nxt = cur ^ 1;
            const ushort* gk = ktile0 + (size_t)(kt + 1) * 4096 + w * 1024 + lane * 8;
            const ushort* gv = vtile0 + (size_t)(kt + 1) * 4096 + w * 1024 + lane * 8;
            gl_lds16(gk,       &Kb[nxt][w * 1024]);
            gl_lds16(gk + 512, &Kb[nxt][w * 1024 + 512]);
            gl_lds16(gv,       &Vb[nxt][w * 1024]);
            gl_lds16(gv + 512, &Vb[nxt][w * 1024 + 512]);
        }

        // ---- frags from LDS (consecutive-16B b128, conflict-free) ----
        short8 kf[4][2], vf[4][2];
        #pragma unroll
        for (int c = 0; c < 4; ++c)
            #pragma unroll
            for (int p = 0; p < 2; ++p) {
                kf[c][p] = *(const short8*)&Kb[cur][(size_t)(((c * 2 + p) * 64) + lane) * 8];
                vf[c][p] = *(const short8*)&Vb[cur][(size_t)(((c * 2 + p) * 64) + lane) * 8];
            }

        // ---- S = Q K^T ----
        floatx4 s[4];
        #pragma unroll
        for (int c = 0; c < 4; ++c) s[c] = (floatx4){0.f, 0.f, 0.f, 0.f};
        #pragma unroll
        for (int c = 0; c < 4; ++c)
            #pragma unroll
            for (int p = 0; p < 2; ++p)
                s[c] = __builtin_amdgcn_mfma_f32_16x16x32_bf16(qf[p], kf[c][p], s[c], 0, 0, 0);

        // ---- causal mask: only the diagonal (last global) tile ----
        if (kt == ntiles - 1) {
            const int qrow0 = qt * 64 + w * 16 + quad * 4;
            const int key0  = kt * 64;
            #pragma unroll
            for (int c = 0; c < 4; ++c)
                #pragma unroll
                for (int reg = 0; reg < 4; ++reg)
                    if (key0 + c * 16 + l16 > qrow0 + reg) s[c][reg] = -1e30f;
        }

        // ---- P = exp(s) -> bf16 -> LDS (C-layout) -> A-frags ----
        #pragma unroll
        for (int c = 0; c < 4; ++c)
            #pragma unroll
            for (int reg = 0; reg < 4; ++reg)
                Pw[(quad * 4 + reg) * 72 + c * 16 + l16] = f2bf(__expf(s[c][reg]));

        short8 pf[2];
        pf[0] = *(const short8*)&Pw[l16 * 72 + quad * 8];
        pf[1] = *(const short8*)&Pw[l16 * 72 + 32 + quad * 8];

        // ---- O += P V ; l += P * ones ----
        #pragma unroll
        for (int p = 0; p < 2; ++p) {
            #pragma unroll
            for (int c = 0; c < 4; ++c)
                o[c] = __builtin_amdgcn_mfma_f32_16x16x32_bf16(pf[p], vf[c][p], o[c], 0, 0, 0);
            osum = __builtin_amdgcn_mfma_f32_16x16x32_bf16(pf[p], ones, osum, 0, 0, 0);
        }
    }

    // ---- write partial: unit = blockIdx.x, 64 rows x 64 cols ----
    const size_t ub = (size_t)blockIdx.x * 4096;
    #pragma unroll
    for (int c = 0; c < 4; ++c)
        #pragma unroll
        for (int reg = 0; reg < 4; ++reg)
            Opart[ub + (w * 16 + quad * 4 + reg) * 64 + c * 16 + l16] = f2bf(o[c][reg]);
    if (l16 == 0) {
        #pragma unroll
        for (int reg = 0; reg < 4; ++reg)
            ml[(size_t)blockIdx.x * 64 + w * 16 + quad * 4 + reg] = osum[reg];
    }
}

// ---------------------------------------------------------------------------
// Kernel 3: merge partials.  out = (sum O_p) / (sum l_p).
// Vectorized this round: 8 B/lane Opart loads (4 rows per wave-instr),
// float4 stores.
// ---------------------------------------------------------------------------
__global__ __launch_bounds__(256) void merge_kernel(
    const ushort* __restrict__ Opart, const float* __restrict__ ml,
    float* __restrict__ out)
{
    const int t    = threadIdx.x;
    const int gw   = blockIdx.x * 4 + (t >> 6);   // 0..2047
    const int lane = t & 63;
    const int b    = gw >> 8;
    const int v    = gw & 255;
    const int qt   = v >> 3;
    const int oct  = v & 7;

    int base, np;
    if (qt >= 24)      { base = (31 - qt) * 4;      np = 4; }
    else if (qt >= 16) { base = 32 + (23 - qt) * 3; np = 3; }
    else if (qt >= 8)  { base = 56 + (15 - qt) * 2; np = 2; }
    else               { base = 72 + (7 - qt);      np = 1; }

    const int r4 = lane >> 4;          // row within 4-row group
    const int cs = (lane & 15) * 4;    // col start (4 cols per lane)
    float* obase = out + ((size_t)b * TT + qt * 64) * HH;

    #pragma unroll
    for (int rg = 0; rg < 2; ++rg) {
        const int row = oct * 8 + rg * 4 + r4;
        float den = 0.f;
        float ax = 0.f, ay = 0.f, az = 0.f, aw = 0.f;
        for (int p = 0; p < np; ++p) {
            const int unit = (base + p) * 8 + b;
            den += ml[(size_t)unit * 64 + row];
            ushort4 ov = *(const ushort4*)&Opart[(size_t)unit * 4096 + row * 64 + cs];
            ax += bf2f(ov.x); ay += bf2f(ov.y); az += bf2f(ov.z); aw += bf2f(ov.w);
        }
        const float inv = 1.0f / den;
        float4 o4;
        o4.x = ax * inv; o4.y = ay * inv; o4.z = az * inv; o4.w = aw * inv;
        *(float4*)&obase[(size_t)row * HH + cs] = o4;
    }
}

// ---------------------------------------------------------------------------
extern "C" void kernel_launch(void* const* d_in, const int* in_sizes, int n_in,
                              void* d_out, int out_size, void* d_ws, size_t ws_size,
                              hipStream_t stream)
{
    (void)in_sizes; (void)n_in; (void)out_size; (void)ws_size;
    const float* x  = (const float*)d_in[0];
    const float* Wq = (const float*)d_in[1];
    const float* Wk = (const float*)d_in[2];
    const float* Wv = (const float*)d_in[3];
    float* outp = (float*)d_out;

    // ws: WbT 384K | qb 2M | kbS 2M | vS 2M | Opart 5.24M | ml 160K (~11.8 MB)
    char* base = (char*)d_ws;
    ushort* WbT   = (ushort*)(base);
    ushort* qbuf  = (ushort*)(base + 393216);
    ushort* kbS   = qbuf + (size_t)BT * HH;
    ushort* vSb   = kbS + (size_t)BT * HH;
    ushort* Opart = vSb + (size_t)BT * HH;
    float*  ml    = (float*)((char*)Opart + (size_t)640 * 4096 * 2);

    wprep_kernel<<<dim3(48),  256, 0, stream>>>(Wq, Wk, Wv, WbT);
    qkv_kernel  <<<dim3(512), 256, 0, stream>>>(x, WbT, qbuf, kbS, vSb);
    attn_kernel <<<dim3(640), 256, 0, stream>>>(qbuf, kbS, vSb, Opart, ml);
    merge_kernel<<<dim3(512), 256, 0, stream>>>(Opart, ml, outp);
}

// Round 2
// 140.049 us; speedup vs baseline: 1.0402x; 1.0027x over previous
//
#include <hip/hip_runtime.h>
#include <hip/hip_bf16.h>
#include <math.h>

#define BB 8
#define TT 2048
#define CC 1024
#define HH 64
#define BT (BB * TT)   // 16384 rows

typedef __attribute__((ext_vector_type(8))) short short8;   // bf16 x8 MFMA frag
typedef __attribute__((ext_vector_type(4))) float floatx4;  // MFMA acc

static __device__ inline ushort f2bf(float f) {
    __hip_bfloat16 h = __float2bfloat16(f);
    return *reinterpret_cast<ushort*>(&h);
}
static __device__ inline unsigned int f2bf2(float lo, float hi) {
    __hip_bfloat162 h = __float22bfloat162_rn(make_float2(lo, hi));
    return *reinterpret_cast<unsigned int*>(&h);
}
static __device__ inline float bf2f(ushort u) {
    union { unsigned int i; float f; } c;
    c.i = ((unsigned int)u) << 16;
    return c.f;
}

// ---------------------------------------------------------------------------
// Kernel 0: W prep (coalesced).  W[k][n] fp32 -> WbT[m][n][k] bf16.
// ---------------------------------------------------------------------------
__global__ __launch_bounds__(256) void wprep_kernel(
    const float* __restrict__ Wq, const float* __restrict__ Wk,
    const float* __restrict__ Wv, ushort* __restrict__ WbT)
{
    __shared__ float ws_[64 * 65];
    const int m  = blockIdx.x >> 4;          // 0..2
    const int kb = (blockIdx.x & 15) * 64;   // 0..960
    const float* W = (m == 0) ? Wq : (m == 1) ? Wk : Wv;
    const int t  = threadIdx.x;
    const int lr = t >> 4, lc = (t & 15) * 4;
    #pragma unroll
    for (int i = 0; i < 4; ++i) {
        const int row = lr + i * 16;
        float4 v = *(const float4*)&W[(size_t)(kb + row) * HH + lc];
        ws_[row * 65 + lc + 0] = v.x; ws_[row * 65 + lc + 1] = v.y;
        ws_[row * 65 + lc + 2] = v.z; ws_[row * 65 + lc + 3] = v.w;
    }
    __syncthreads();
    const int n = t & 63, kseg = t >> 6;     // kseg 0..3 -> 16 k each
    union { ushort s[16]; uint4 q[2]; } u;
    #pragma unroll
    for (int j = 0; j < 16; ++j)
        u.s[j] = f2bf(ws_[(kseg * 16 + j) * 65 + n]);
    ushort* dst = &WbT[(size_t)(m * 64 + n) * 1024 + kb + kseg * 16];
    *(uint4*)&dst[0] = u.q[0];
    *(uint4*)&dst[8] = u.q[1];
}

// ---------------------------------------------------------------------------
// Kernel 1: QKV via bf16 MFMA (unchanged this round).
// ---------------------------------------------------------------------------
__global__ __launch_bounds__(256) void qkv_kernel(
    const float* __restrict__ x, const ushort* __restrict__ WbT,
    ushort* __restrict__ qb, ushort* __restrict__ kbS, ushort* __restrict__ vS)
{
    __shared__ ushort As[2][256 * 8];   // frag-major: slot = (p*2+mt)*64 + l16*4 + quad

    const int row0 = blockIdx.x * 32;
    const int t    = threadIdx.x;
    const int w    = t >> 6;
    const int lane = t & 63;
    const int l16  = lane & 15;
    const int quad = lane >> 4;
    const int ct0  = w * 3;

    const int srow = t >> 3, sseg = t & 7;
    const int slot = (((sseg >> 2) * 2 + (srow >> 4)) * 16 + (srow & 15)) * 4 + (sseg & 3);
    const float* xsrc = &x[(size_t)(row0 + srow) * CC + sseg * 8];

    floatx4 acc[2][3];
    #pragma unroll
    for (int mt = 0; mt < 2; ++mt)
        #pragma unroll
        for (int c = 0; c < 3; ++c) acc[mt][c] = (floatx4){0.f, 0.f, 0.f, 0.f};

    // ---- depth-2 register prefetch of x ----
    float4 xa0 = *(const float4*)&xsrc[0];
    float4 xb0 = *(const float4*)&xsrc[4];
    float4 xa1 = *(const float4*)&xsrc[64];
    float4 xb1 = *(const float4*)&xsrc[68];

    short8 bfr[2][3];
    #pragma unroll
    for (int p = 0; p < 2; ++p)
        #pragma unroll
        for (int c = 0; c < 3; ++c)
            bfr[p][c] = *(const short8*)&WbT[(size_t)((ct0 + c) * 16 + l16) * 1024
                                             + p * 32 + quad * 8];

    auto body = [&](int it, float4& xa, float4& xb) {
        uint4 uq;
        uq.x = f2bf2(xa.x, xa.y); uq.y = f2bf2(xa.z, xa.w);
        uq.z = f2bf2(xb.x, xb.y); uq.w = f2bf2(xb.z, xb.w);
        *(uint4*)&As[it & 1][slot * 8] = uq;
        __syncthreads();

        if (it + 2 < 16) {
            xa = *(const float4*)&xsrc[(it + 2) * 64 + 0];
            xb = *(const float4*)&xsrc[(it + 2) * 64 + 4];
        }
        short8 bnx[2][3];
        if (it < 15) {
            const int kn = (it + 1) * 64;
            #pragma unroll
            for (int p = 0; p < 2; ++p)
                #pragma unroll
                for (int c = 0; c < 3; ++c)
                    bnx[p][c] = *(const short8*)&WbT[(size_t)((ct0 + c) * 16 + l16) * 1024
                                                     + kn + p * 32 + quad * 8];
        }

        #pragma unroll
        for (int p = 0; p < 2; ++p) {
            short8 a0 = *(const short8*)&As[it & 1][(size_t)((p * 2 + 0) * 64 + l16 * 4 + quad) * 8];
            short8 a1 = *(const short8*)&As[it & 1][(size_t)((p * 2 + 1) * 64 + l16 * 4 + quad) * 8];
            #pragma unroll
            for (int c = 0; c < 3; ++c) {
                acc[0][c] = __builtin_amdgcn_mfma_f32_16x16x32_bf16(a0, bfr[p][c], acc[0][c], 0, 0, 0);
                acc[1][c] = __builtin_amdgcn_mfma_f32_16x16x32_bf16(a1, bfr[p][c], acc[1][c], 0, 0, 0);
            }
        }
        #pragma unroll
        for (int p = 0; p < 2; ++p)
            #pragma unroll
            for (int c = 0; c < 3; ++c)
                bfr[p][c] = bnx[p][c];
    };

    for (int it2 = 0; it2 < 16; it2 += 2) {
        body(it2 + 0, xa0, xb0);
        body(it2 + 1, xa1, xb1);
    }

    // ---- epilogue ----
    const int half = (row0 >> 5) & 1;              // which 32-row half of the 64-tile
    const size_t tile = (size_t)(row0 >> 6) * 4096;
    #pragma unroll
    for (int c = 0; c < 3; ++c) {
        const int ct    = ct0 + c;
        const int mtype = ct >> 2;
        const int n0    = (ct & 3) * 16;
        #pragma unroll
        for (int mt = 0; mt < 2; ++mt) {
            const int row = row0 + mt * 16 + quad * 4;
            if (mtype == 0) {                       // q: row-major, /8 folded
                #pragma unroll
                for (int reg = 0; reg < 4; ++reg)
                    qb[(size_t)(row + reg) * HH + n0 + l16] = f2bf(acc[mt][c][reg] * 0.125f);
            } else if (mtype == 1) {                // K swizzled (B-frag order)
                const int cP    = half * 2 + mt;
                const int pP    = (ct & 3) >> 1;
                const int quadP = ((ct & 3) * 2 + (l16 >> 3)) & 3;
                const int jP    = l16 & 7;
                const int ub    = (cP * 2 + pP) * 64 + quadP * 16;
                #pragma unroll
                for (int reg = 0; reg < 4; ++reg)
                    kbS[tile + (size_t)(ub + quad * 4 + reg) * 8 + jP] = f2bf(acc[mt][c][reg]);
            } else {                                // V swizzled (B-frag order)
                const int cp2 = (ct & 3) * 2 + half;   // c'*2 + p'
                #pragma unroll
                for (int reg = 0; reg < 4; ++reg) {
                    const int rq    = quad * 4 + reg;
                    const int quadP = mt * 2 + (rq >> 3);
                    vS[tile + (size_t)(cp2 * 64 + quadP * 16 + l16) * 8 + (rq & 7)] = f2bf(acc[mt][c][reg]);
                }
            }
        }
    }
}

// ---------------------------------------------------------------------------
// Kernel 2: split-K MFMA flash attention, REWRITTEN this round:
//  - K/V fragments loaded DIRECTLY from global (kbS/vS are L2-resident and
//    already in frag order -> 1KB/instr coalesced loads).  No LDS staging,
//    no double buffers, NO barriers at all -> waves fully independent.
//  - QK^T computed operand-swapped: S^T = mfma(K,Q).  Lane then holds 4
//    CONSECUTIVE keys (reg) for one q (=l16) -> P write is 8 cvt_pk +
//    4 ds_write_b64 instead of 16 scalar ds_write_b16 + 16 f2bf.
//    PV-side pf b128 reads are unchanged (identical P layout/content).
//  - s_setprio(1) around MFMA clusters (independent-wave regime, T5/m191).
// ---------------------------------------------------------------------------
__global__ __launch_bounds__(256) void attn_kernel(
    const ushort* __restrict__ qb, const ushort* __restrict__ kbS,
    const ushort* __restrict__ vS, ushort* __restrict__ Opart,
    float* __restrict__ ml)
{
    __shared__ __align__(16) ushort P[4][16 * 72];   // per-wave P tile

    const int t    = threadIdx.x;
    const int w    = t >> 6;
    const int lane = t & 63;
    const int l16  = lane & 15;
    const int quad = lane >> 4;

    const int b   = blockIdx.x & 7;
    const int idx = blockIdx.x >> 3;   // 0..79, heavy-first
    int qt, part, np;
    if (idx < 32)      { qt = 31 - (idx >> 2); part = idx & 3; np = 4; }
    else if (idx < 56) { const int u = idx - 32; const int g = u / 3;
                         qt = 23 - g; part = u - g * 3; np = 3; }
    else if (idx < 72) { const int u = idx - 56; qt = 15 - (u >> 1); part = u & 1; np = 2; }
    else               { qt = 7 - (idx - 72); part = 0; np = 1; }
    const int ntiles = qt + 1;
    const int ktb = (part * ntiles) / np;
    const int kte = ((part + 1) * ntiles) / np;

    const ushort* ktile0 = kbS + (size_t)(b * 32) * 4096;
    const ushort* vtile0 = vS  + (size_t)(b * 32) * 4096;

    // Q frags: rows qt*64 + w*16 + l16 (used as B-operand of swapped QK^T;
    // the B-frag lane map is identical to the A-frag map, so same loads).
    short8 qf[2];
    {
        const ushort* qrow = qb + ((size_t)b * TT + qt * 64 + w * 16) * HH;
        qf[0] = *(const short8*)&qrow[l16 * HH + quad * 8];
        qf[1] = *(const short8*)&qrow[l16 * HH + 32 + quad * 8];
    }
    short8 ones;
    #pragma unroll
    for (int i = 0; i < 8; ++i) ones[i] = (short)0x3F80;   // bf16 1.0

    floatx4 o[4], osum;
    #pragma unroll
    for (int c = 0; c < 4; ++c) o[c] = (floatx4){0.f, 0.f, 0.f, 0.f};
    osum = (floatx4){0.f, 0.f, 0.f, 0.f};

    ushort* Pw = &P[w][0];

    for (int kt = ktb; kt < kte; ++kt) {
        const ushort* kg = ktile0 + (size_t)kt * 4096;
        const ushort* vg = vtile0 + (size_t)kt * 4096;

        // ---- frag loads straight from global (L2-hit, frag-ordered) ----
        short8 kf[4][2], vf[4][2];
        #pragma unroll
        for (int c = 0; c < 4; ++c)
            #pragma unroll
            for (int p = 0; p < 2; ++p) {
                kf[c][p] = *(const short8*)&kg[(size_t)(((c * 2 + p) * 64) + lane) * 8];
                vf[c][p] = *(const short8*)&vg[(size_t)(((c * 2 + p) * 64) + lane) * 8];
            }

        // ---- S^T = K Q^T (operand-swapped): row=key chunk, col=q ----
        floatx4 s[4];
        #pragma unroll
        for (int c = 0; c < 4; ++c) s[c] = (floatx4){0.f, 0.f, 0.f, 0.f};
        __builtin_amdgcn_s_setprio(1);
        #pragma unroll
        for (int c = 0; c < 4; ++c)
            #pragma unroll
            for (int p = 0; p < 2; ++p)
                s[c] = __builtin_amdgcn_mfma_f32_16x16x32_bf16(kf[c][p], qf[p], s[c], 0, 0, 0);
        __builtin_amdgcn_s_setprio(0);

        // ---- causal mask (roles swapped: key from reg, q from l16) ----
        if (kt == ntiles - 1) {
            const int key0 = kt * 64 + quad * 4;
            const int qrow = qt * 64 + w * 16 + l16;
            #pragma unroll
            for (int c = 0; c < 4; ++c)
                #pragma unroll
                for (int reg = 0; reg < 4; ++reg)
                    if (key0 + c * 16 + reg > qrow) s[c][reg] = -1e30f;
        }

        // ---- P = exp(s^T) -> packed bf16 -> LDS row q=l16, keys contiguous ----
        #pragma unroll
        for (int c = 0; c < 4; ++c) {
            uint2 u;
            u.x = f2bf2(__expf(s[c][0]), __expf(s[c][1]));
            u.y = f2bf2(__expf(s[c][2]), __expf(s[c][3]));
            *(uint2*)&Pw[l16 * 72 + c * 16 + quad * 4] = u;
        }

        short8 pf[2];
        pf[0] = *(const short8*)&Pw[l16 * 72 + quad * 8];
        pf[1] = *(const short8*)&Pw[l16 * 72 + 32 + quad * 8];

        // ---- O += P V ; l += P * ones ----
        __builtin_amdgcn_s_setprio(1);
        #pragma unroll
        for (int p = 0; p < 2; ++p) {
            #pragma unroll
            for (int c = 0; c < 4; ++c)
                o[c] = __builtin_amdgcn_mfma_f32_16x16x32_bf16(pf[p], vf[c][p], o[c], 0, 0, 0);
            osum = __builtin_amdgcn_mfma_f32_16x16x32_bf16(pf[p], ones, osum, 0, 0, 0);
        }
        __builtin_amdgcn_s_setprio(0);
    }

    // ---- write partial: unit = blockIdx.x, 64 rows x 64 cols ----
    const size_t ub = (size_t)blockIdx.x * 4096;
    #pragma unroll
    for (int c = 0; c < 4; ++c)
        #pragma unroll
        for (int reg = 0; reg < 4; ++reg)
            Opart[ub + (w * 16 + quad * 4 + reg) * 64 + c * 16 + l16] = f2bf(o[c][reg]);
    if (l16 == 0) {
        #pragma unroll
        for (int reg = 0; reg < 4; ++reg)
            ml[(size_t)blockIdx.x * 64 + w * 16 + quad * 4 + reg] = osum[reg];
    }
}

// ---------------------------------------------------------------------------
// Kernel 3: merge partials.  out = (sum O_p) / (sum l_p).
// ---------------------------------------------------------------------------
__global__ __launch_bounds__(256) void merge_kernel(
    const ushort* __restrict__ Opart, const float* __restrict__ ml,
    float* __restrict__ out)
{
    const int t    = threadIdx.x;
    const int gw   = blockIdx.x * 4 + (t >> 6);   // 0..2047
    const int lane = t & 63;
    const int b    = gw >> 8;
    const int v    = gw & 255;
    const int qt   = v >> 3;
    const int oct  = v & 7;

    int base, np;
    if (qt >= 24)      { base = (31 - qt) * 4;      np = 4; }
    else if (qt >= 16) { base = 32 + (23 - qt) * 3; np = 3; }
    else if (qt >= 8)  { base = 56 + (15 - qt) * 2; np = 2; }
    else               { base = 72 + (7 - qt);      np = 1; }

    const int r4 = lane >> 4;          // row within 4-row group
    const int cs = (lane & 15) * 4;    // col start (4 cols per lane)
    float* obase = out + ((size_t)b * TT + qt * 64) * HH;

    #pragma unroll
    for (int rg = 0; rg < 2; ++rg) {
        const int row = oct * 8 + rg * 4 + r4;
        float den = 0.f;
        float ax = 0.f, ay = 0.f, az = 0.f, aw = 0.f;
        for (int p = 0; p < np; ++p) {
            const int unit = (base + p) * 8 + b;
            den += ml[(size_t)unit * 64 + row];
            ushort4 ov = *(const ushort4*)&Opart[(size_t)unit * 4096 + row * 64 + cs];
            ax += bf2f(ov.x); ay += bf2f(ov.y); az += bf2f(ov.z); aw += bf2f(ov.w);
        }
        const float inv = 1.0f / den;
        float4 o4;
        o4.x = ax * inv; o4.y = ay * inv; o4.z = az * inv; o4.w = aw * inv;
        *(float4*)&obase[(size_t)row * HH + cs] = o4;
    }
}

// ---------------------------------------------------------------------------
extern "C" void kernel_launch(void* const* d_in, const int* in_sizes, int n_in,
                              void* d_out, int out_size, void* d_ws, size_t ws_size,
                              hipStream_t stream)
{
    (void)in_sizes; (void)n_in; (void)out_size; (void)ws_size;
    const float* x  = (const float*)d_in[0];
    const float* Wq = (const float*)d_in[1];
    const float* Wk = (const float*)d_in[2];
    const float* Wv = (const float*)d_in[3];
    float* outp = (float*)d_out;

    // ws: WbT 384K | qb 2M | kbS 2M | vS 2M | Opart 5.24M | ml 160K (~11.8 MB)
    char* base = (char*)d_ws;
    ushort* WbT   = (ushort*)(base);
    ushort* qbuf  = (ushort*)(base + 393216);
    ushort* kbS   = qbuf + (size_t)BT * HH;
    ushort* vSb   = kbS + (size_t)BT * HH;
    ushort* Opart = vSb + (size_t)BT * HH;
    float*  ml    = (float*)((char*)Opart + (size_t)640 * 4096 * 2);

    wprep_kernel<<<dim3(48),  256, 0, stream>>>(Wq, Wk, Wv, WbT);
    qkv_kernel  <<<dim3(512), 256, 0, stream>>>(x, WbT, qbuf, kbS, vSb);
    attn_kernel <<<dim3(640), 256, 0, stream>>>(qbuf, kbS, vSb, Opart, ml);
    merge_kernel<<<dim3(512), 256, 0, stream>>>(Opart, ml, outp);
}